// Round 2
// baseline (84.723 us; speedup 1.0000x reference)
//
#include <hip/hip_runtime.h>

// Problem constants (from reference setup_inputs)
#define BB  2
#define TT  4
#define CC  256
#define HH  64
#define WW  176
#define NN  900
#define PP  8
#define NTF 3
#define NSF 3

#define HW        (HH * WW)              // 11264
#define NPOINTS   (BB * NN * PP)         // 14400
#define W16       11                     // ceil(176/16) line-buckets along w
#define NBUCKET   (BB * NTF * HH * W16)  // 4224
#define BPF       (HH * W16)             // 704 buckets per (b,frame)
#define SCAN_PER  17                     // 256*17 = 4352 >= 4224
#define GATHER_G  8
#define NGBLK     (NPOINTS / GATHER_G)   // 1800 (fallback path)
#define NBF       (BB * NTF)             // 6 (b,frame) images per cam
#define SPB       16                     // sorted points per block in pass B

// passA: 2-h-row slices (1.4 KB), persistent waves, async LDS pipeline
#define HSL          2
#define SLICE_FLOATS (HSL * WW)          // 352
#define SLICE_F4     (SLICE_FLOATS / 4)  // 88
#define SLICE_BKT    (HSL * W16)         // 22 buckets per slice
#define SLICES       32                  // per (cam,bf,c) image-row
#define NITEMS       (2 * NBF * CC * SLICES)  // 98304 staging items
#define PA_BLOCKS    2048
#define PA_WAVES     (PA_BLOCKS * 4)     // 8192
#define ITEMS_PW     (NITEMS / PA_WAVES) // 12
#define DEPTH        6                   // LDS slots (6-deep burst pipeline)

// native vector type (accepted by __builtin_nontemporal_* unlike HIP float4)
typedef float f32x4 __attribute__((ext_vector_type(4)));

// ws layout (int32 slots)
#define WS_HIST   0
#define WS_OFFS   (WS_HIST + NBUCKET)
#define WS_KEY    (WS_OFFS + NBUCKET + 1)   // +1: sentinel offs[NBUCKET]=NPOINTS
#define WS_RANK   (WS_KEY + NPOINTS)
#define WS_REM    (WS_RANK + NPOINTS)
#define WS_BASE   (WS_REM + NPOINTS)
#define WS_SREM   (WS_BASE + NPOINTS)
#define WS_SBASE  (WS_SREM + NPOINTS)
#define WS_SPT    (WS_SBASE + NPOINTS)
#define WS_INTS   (WS_SPT + NPOINTS)
// compact buffer: [cam*256+c][sortedPos] floats, 256B-aligned
#define WS_COMPACT_OFF (((WS_INTS * 4) + 255) & ~255)
#define COMPACT_FLOATS ((size_t)(2 * CC) * NPOINTS)         // 7,372,800
#define WS_NEEDED      (WS_COMPACT_OFF + COMPACT_FLOATS * 4)

// ---- K0: zero histogram + write index passthroughs (as float) -------------
__global__ __launch_bounds__(256) void k0_zero_idx(
    const int* __restrict__ tIdx, const int* __restrict__ sIdx,
    const int* __restrict__ pIdx, float* __restrict__ outIdx,
    int* __restrict__ hist)
{
    const int gid = blockIdx.x * 256 + threadIdx.x;
    if (gid < NBUCKET) hist[gid] = 0;
    const int nT = BB * NN * NTF, nS = BB * NN * NSF, nP = NPOINTS;
    if (gid < nT)                 outIdx[gid] = (float)tIdx[gid];
    else if (gid < nT + nS)       outIdx[gid] = (float)sIdx[gid - nT];
    else if (gid < nT + nS + nP)  outIdx[gid] = (float)pIdx[gid - nT - nS];
}

// ---- K1: decode chain, bucket key, histogram ------------------------------
__global__ __launch_bounds__(256) void k1_prep(
    const int* __restrict__ tIdx, const int* __restrict__ sIdx,
    const int* __restrict__ pIdx,
    int* __restrict__ hist, int* __restrict__ key,
    int* __restrict__ rank, int* __restrict__ remArr,
    int* __restrict__ baseArr)
{
    const int pt = blockIdx.x * 256 + threadIdx.x;
    if (pt >= NPOINTS) return;
    const int b  = pt / (NN * PP);
    const int n  = (pt - b * NN * PP) >> 3;     // / PP
    const int bn = b * NN + n;

    const int pi  = pIdx[pt];
    const int s   = pi / (NTF * HW);
    const int rem = pi % HW;                    // h*W + w
    const int h   = rem / WW;
    const int w   = rem - h * WW;

    const int sp    = sIdx[bn * NSF + s];
    const int frame = tIdx[bn * NTF + sp];

    const int base = ((b * TT + frame) * CC) * HW + rem;   // c=0 elem offset
    const int k    = ((b * NTF + frame) * HH + h) * W16 + (w >> 4);
    const int r    = atomicAdd(&hist[k], 1);
    key[pt] = k; rank[pt] = r; remArr[pt] = rem; baseArr[pt] = base;
}

// ---- K2: exclusive scan of 4224 bucket counts (single block, shfl) --------
__global__ __launch_bounds__(256) void k2_scan(
    const int* __restrict__ hist, int* __restrict__ offs)
{
    __shared__ int wsum[4];
    const int t = threadIdx.x;
    const int lane = t & 63, wv = t >> 6;
    int local[SCAN_PER];
    int sum = 0;
    for (int i = 0; i < SCAN_PER; ++i) {
        const int idx = t * SCAN_PER + i;
        const int v = (idx < NBUCKET) ? hist[idx] : 0;
        local[i] = sum;           // exclusive within this thread's chunk
        sum += v;
    }
    // wave-inclusive scan of per-thread sums
    int incl = sum;
    for (int d = 1; d < 64; d <<= 1) {
        const int up = __shfl_up(incl, d, 64);
        if (lane >= d) incl += up;
    }
    if (lane == 63) wsum[wv] = incl;
    __syncthreads();
    int wpre = 0;
    for (int k = 0; k < 4; ++k) if (k < wv) wpre += wsum[k];
    const int base = wpre + incl - sum;   // exclusive prefix of this thread
    for (int i = 0; i < SCAN_PER; ++i) {
        const int idx = t * SCAN_PER + i;
        if (idx < NBUCKET) offs[idx] = base + local[i];
    }
    if (t == 255) offs[NBUCKET] = wpre + incl;  // total = NPOINTS sentinel
}

// ---- K3: scatter points into bucket-sorted order --------------------------
__global__ __launch_bounds__(256) void k3_scatter(
    const int* __restrict__ key, const int* __restrict__ rank,
    const int* __restrict__ remArr, const int* __restrict__ baseArr,
    const int* __restrict__ offs,
    int* __restrict__ sRem, int* __restrict__ sBase, int* __restrict__ sPt)
{
    const int pt = blockIdx.x * 256 + threadIdx.x;
    if (pt >= NPOINTS) return;
    const int pos = offs[key[pt]] + rank[pt];
    sRem[pos]  = remArr[pt];
    sBase[pos] = baseArr[pt];
    sPt[pos]   = pt;
}

// ---- K4a: persistent async stream-gather, 6-deep burst vmcnt pipeline -----
// Staging uses global_load_lds (async, no VGPR round-trip, vmcnt-tracked).
// All per-item offs/sRem values preloaded into registers, then vmcnt(0):
// afterwards the vmcnt stream is EXACTLY 2 staging loads + 2 stores per
// item. Prologue bursts 6 items (12 back-to-back loads, ~8.4 KB/wave in
// flight) before the first wait; steady state {issue(i+6); gather(i)} with
// exact counted waits (FIFO-derived: 12,14,16,18,20,22 | 22,20,18,16,14,12
// -- never 0 in the stream). Stores are made exactly-2 via idempotent
// clamped writes (lanes past segment end rewrite dst[E-1] with its correct
// value). Segments >128 pts (P ~ e-33) handled in epilogue.
#define GLOAD_LDS(GP, LP)                                                      \
    __builtin_amdgcn_global_load_lds(                                          \
        (const __attribute__((address_space(1))) void*)(GP),                   \
        (__attribute__((address_space(3))) void*)(LP), 16, 0, 0)

#define PA_ISSUE(SLOT, IT) {                                                   \
    const int q_     = q0 + (IT);                                              \
    const int slice_ = q_ & 31;                                                \
    const int cq_    = q_ >> 5;                                                \
    const int c_     = cq_ & 255;                                              \
    const int bfcam_ = cq_ >> 8;                                               \
    const int cam_   = (bfcam_ >= NBF) ? 1 : 0;                                \
    const int bf_    = bfcam_ - cam_ * NBF;                                    \
    const int b_     = bf_ / NTF;                                              \
    const int fr_    = bf_ - b_ * NTF;                                         \
    const float* src_ = (cam_ ? cam1 : cam0)                                   \
        + (size_t)((b_ * TT + fr_) * CC + c_) * HW + slice_ * SLICE_FLOATS;    \
    GLOAD_LDS(src_ + lane * 4, &rows[wv][SLOT][0]);                            \
    if (lane < (SLICE_F4 - 64)) GLOAD_LDS(src_ + 256 + lane * 4,               \
                                          &rows[wv][SLOT][256]);               \
}

#define PA_GATHER(SLOT, IT, NW) {                                              \
    asm volatile("s_waitcnt vmcnt(" #NW ")" ::: "memory");                     \
    const int q_     = q0 + (IT);                                              \
    const int slice_ = q_ & 31;                                                \
    const int cq_    = q_ >> 5;                                                \
    const int c_     = cq_ & 255;                                              \
    const int bfcam_ = cq_ >> 8;                                               \
    const int cam_   = (bfcam_ >= NBF) ? 1 : 0;                                \
    const int br_    = slice_ * SLICE_FLOATS;                                  \
    float* dst_ = compact + (size_t)(cam_ * CC + c_) * NPOINTS;                \
    const int S_  = segS[IT];                                                  \
    const int E1_ = segE[IT] - 1;                                              \
    int jj0_ = S_ + lane;       if (jj0_ > E1_) jj0_ = E1_;                    \
    int jj1_ = S_ + 64 + lane;  if (jj1_ > E1_) jj1_ = E1_;                    \
    dst_[jj0_] = rows[wv][SLOT][r0a[IT] - br_];                                \
    dst_[jj1_] = rows[wv][SLOT][r1a[IT] - br_];                                \
}

__global__ __launch_bounds__(256) void k4_passA(
    const float* __restrict__ cam0, const float* __restrict__ cam1,
    const int* __restrict__ offs, const int* __restrict__ sRem,
    float* __restrict__ compact)
{
    __shared__ float rows[4][DEPTH][SLICE_FLOATS];   // 33792 B
    const int wv   = threadIdx.x >> 6;
    const int lane = threadIdx.x & 63;
    const int q0   = (blockIdx.x * 4 + wv) * ITEMS_PW;

    // ---- preload all per-item metadata (keeps vmcnt stream clean after) ---
    int segS[ITEMS_PW], segE[ITEMS_PW], r0a[ITEMS_PW], r1a[ITEMS_PW];
#pragma unroll
    for (int it = 0; it < ITEMS_PW; ++it) {
        const int q_     = q0 + it;
        const int slice_ = q_ & 31;
        const int cq_    = q_ >> 5;
        const int bfcam_ = cq_ >> 8;
        const int cam_   = (bfcam_ >= NBF) ? 1 : 0;
        const int bf_    = bfcam_ - cam_ * NBF;
        const int bs_    = bf_ * BPF + slice_ * SLICE_BKT;
        segS[it] = offs[bs_];
        segE[it] = offs[bs_ + SLICE_BKT];
    }
#pragma unroll
    for (int it = 0; it < ITEMS_PW; ++it) {
        const int E1 = segE[it] - 1;
        int a0 = segS[it] + lane;       if (a0 > E1) a0 = E1;
        int a1 = segS[it] + 64 + lane;  if (a1 > E1) a1 = E1;
        r0a[it] = sRem[a0];
        r1a[it] = sRem[a1];
    }
    asm volatile("s_waitcnt vmcnt(0)" ::: "memory");

    // ---- burst prologue: 6 items (12 loads) in flight ----
    PA_ISSUE(0, 0)
    PA_ISSUE(1, 1)
    PA_ISSUE(2, 2)
    PA_ISSUE(3, 3)
    PA_ISSUE(4, 4)
    PA_ISSUE(5, 5)

    // ---- steady state: issue(i+6) then gather(i) with exact counted waits -
    PA_ISSUE(0, 6)   PA_GATHER(0, 0, 12)
    PA_ISSUE(1, 7)   PA_GATHER(1, 1, 14)
    PA_ISSUE(2, 8)   PA_GATHER(2, 2, 16)
    PA_ISSUE(3, 9)   PA_GATHER(3, 3, 18)
    PA_ISSUE(4, 10)  PA_GATHER(4, 4, 20)
    PA_ISSUE(5, 11)  PA_GATHER(5, 5, 22)
                     PA_GATHER(0, 6, 22)
                     PA_GATHER(1, 7, 20)
                     PA_GATHER(2, 8, 18)
                     PA_GATHER(3, 9, 16)
                     PA_GATHER(4, 10, 14)
                     PA_GATHER(5, 11, 12)

    // ---- epilogue: segments longer than 128 points (essentially never) ----
    asm volatile("s_waitcnt vmcnt(0)" ::: "memory");
#pragma unroll
    for (int it = 0; it < ITEMS_PW; ++it) {
        if (segE[it] - segS[it] > 128) {
            const int q_     = q0 + it;
            const int slice_ = q_ & 31;
            const int cq_    = q_ >> 5;
            const int c_     = cq_ & 255;
            const int bfcam_ = cq_ >> 8;
            const int cam_   = (bfcam_ >= NBF) ? 1 : 0;
            const int bf_    = bfcam_ - cam_ * NBF;
            const int b_     = bf_ / NTF;
            const int fr_    = bf_ - b_ * NTF;
            const float* srcrow = (cam_ ? cam1 : cam0)
                                + (size_t)((b_ * TT + fr_) * CC + c_) * HW;
            float* dst_ = compact + (size_t)(cam_ * CC + c_) * NPOINTS;
            for (int j = segS[it] + 128 + lane; j < segE[it]; j += 64)
                dst_[j] = srcrow[sRem[j]];
        }
    }
}

// ---- K5: permute compact -> out -------------------------------------------
// compact is dead after this kernel and out is never re-read by kernels:
// use non-temporal accesses so neither evicts the LLC-resident feature maps.
__global__ __launch_bounds__(256) void k5_passB(
    const float* __restrict__ compact, const int* __restrict__ sPt,
    float* __restrict__ out)
{
    const int sp0 = blockIdx.x * SPB;
    const int c   = threadIdx.x;

    int pts[SPB];
#pragma unroll
    for (int i = 0; i < SPB; ++i) pts[i] = sPt[sp0 + i];

    const f32x4* r0 = (const f32x4*)(compact + (size_t)c * NPOINTS + sp0);
    const f32x4* r1 = (const f32x4*)(compact + (size_t)(CC + c) * NPOINTS + sp0);
    f32x4 a0[SPB / 4], a1[SPB / 4];
#pragma unroll
    for (int q = 0; q < SPB / 4; ++q) {
        a0[q] = __builtin_nontemporal_load(&r0[q]);
        a1[q] = __builtin_nontemporal_load(&r1[q]);
    }

#pragma unroll
    for (int q = 0; q < SPB / 4; ++q) {
#pragma unroll
        for (int r = 0; r < 4; ++r) {
            const size_t ob = (size_t)pts[q * 4 + r] * (2 * CC);
            __builtin_nontemporal_store(a0[q][r], &out[ob + c]);
            __builtin_nontemporal_store(a1[q][r], &out[ob + CC + c]);
        }
    }
}

// ---- K4b (fallback path): scattered gather in bucket-sorted order ---------
__global__ __launch_bounds__(256) void k4_gather(
    const float* __restrict__ cam0, const float* __restrict__ cam1,
    const int* __restrict__ sortedBase, const int* __restrict__ sortedPt,
    float* __restrict__ out)
{
    const int chunk = (blockIdx.x & 7) * (NGBLK / 8) + (blockIdx.x >> 3);
    const int c     = threadIdx.x;
    const int start = chunk * GATHER_G;

    int bases[GATHER_G], pts[GATHER_G];
#pragma unroll
    for (int g = 0; g < GATHER_G; ++g) {
        bases[g] = sortedBase[start + g];
        pts[g]   = sortedPt[start + g];
    }
    float v0[GATHER_G], v1[GATHER_G];
#pragma unroll
    for (int g = 0; g < GATHER_G; ++g) {
        v0[g] = cam0[bases[g] + c * HW];
        v1[g] = cam1[bases[g] + c * HW];
    }
#pragma unroll
    for (int g = 0; g < GATHER_G; ++g) {
        const int obase = pts[g] * (2 * CC);
        out[obase + c]      = v0[g];
        out[obase + CC + c] = v1[g];
    }
}

extern "C" void kernel_launch(void* const* d_in, const int* in_sizes, int n_in,
                              void* d_out, int out_size, void* d_ws, size_t ws_size,
                              hipStream_t stream) {
    const float* cam0 = (const float*)d_in[0];
    const float* cam1 = (const float*)d_in[1];
    // d_in[2] = anchor_centers (unused)
    const int* tIdx = (const int*)d_in[3];
    const int* sIdx = (const int*)d_in[4];
    const int* pIdx = (const int*)d_in[5];

    float* out = (float*)d_out;
    int*   ws  = (int*)d_ws;

    int* hist  = ws + WS_HIST;
    int* offs  = ws + WS_OFFS;
    int* key   = ws + WS_KEY;
    int* rank  = ws + WS_RANK;
    int* rem   = ws + WS_REM;
    int* baseA = ws + WS_BASE;
    int* sRem  = ws + WS_SREM;
    int* sBase = ws + WS_SBASE;
    int* sPt   = ws + WS_SPT;
    float* compact = (float*)((char*)d_ws + WS_COMPACT_OFF);

    const int nSampled = BB * NN * PP * 2 * CC;        // 7,372,800
    const int nIdxTot  = BB * NN * (NTF + NSF + PP);   // 25,200

    k0_zero_idx<<<(nIdxTot + 255) / 256, 256, 0, stream>>>(
        tIdx, sIdx, pIdx, out + nSampled, hist);

    k1_prep<<<(NPOINTS + 255) / 256, 256, 0, stream>>>(
        tIdx, sIdx, pIdx, hist, key, rank, rem, baseA);

    k2_scan<<<1, 256, 0, stream>>>(hist, offs);

    k3_scatter<<<(NPOINTS + 255) / 256, 256, 0, stream>>>(
        key, rank, rem, baseA, offs, sRem, sBase, sPt);

    if (ws_size >= WS_NEEDED) {
        k4_passA<<<PA_BLOCKS, 256, 0, stream>>>(cam0, cam1, offs, sRem, compact);
        k5_passB<<<NPOINTS / SPB, 256, 0, stream>>>(compact, sPt, out);
    } else {
        k4_gather<<<NGBLK, 256, 0, stream>>>(cam0, cam1, sBase, sPt, out);
    }
}

// Round 3
// 61.795 us; speedup vs baseline: 1.3710x; 1.3710x over previous
//
#include <hip/hip_runtime.h>

// Problem constants (from reference setup_inputs)
#define BB  2
#define TT  4
#define CC  256
#define HH  64
#define WW  176
#define NN  900
#define PP  8
#define NTF 3
#define NSF 3

#define HW        (HH * WW)              // 11264
#define NPOINTS   (BB * NN * PP)         // 14400
#define W16       11                     // ceil(176/16) line-buckets along w
#define NBUCKET   (BB * NTF * HH * W16)  // 4224
#define BPF       (HH * W16)             // 704 buckets per (b,frame)
#define SCAN_PER  17                     // 256*17 = 4352 >= 4224
#define GATHER_G  8
#define NGBLK     (NPOINTS / GATHER_G)   // 1800 (fallback path)
#define NBF       (BB * NTF)             // 6 (b,frame) images per cam
#define SPB       16                     // sorted points per block in pass B

// passA: 2-h-row slices (1.4 KB), persistent waves, register-staged pipeline
#define HSL          2
#define SLICE_FLOATS (HSL * WW)          // 352
#define SLICE_F4     (SLICE_FLOATS / 4)  // 88
#define SLICE_BKT    (HSL * W16)         // 22 buckets per slice
#define SLICES       32                  // per (cam,bf,c) image-row
#define NITEMS       (2 * NBF * CC * SLICES)  // 98304 staging items
#define PA_BLOCKS    2048
#define PA_WAVES     (PA_BLOCKS * 4)     // 8192
#define ITEMS_PW     (NITEMS / PA_WAVES) // 12

// native vector type
typedef float f32x4 __attribute__((ext_vector_type(4)));

// ws layout (int32 slots)
#define WS_HIST   0
#define WS_OFFS   (WS_HIST + NBUCKET)
#define WS_KEY    (WS_OFFS + NBUCKET + 1)   // +1: sentinel offs[NBUCKET]=NPOINTS
#define WS_RANK   (WS_KEY + NPOINTS)
#define WS_REM    (WS_RANK + NPOINTS)
#define WS_BASE   (WS_REM + NPOINTS)
#define WS_SREM   (WS_BASE + NPOINTS)
#define WS_SBASE  (WS_SREM + NPOINTS)
#define WS_SPT    (WS_SBASE + NPOINTS)
#define WS_INTS   (WS_SPT + NPOINTS)
// compact buffer: [cam*256+c][sortedPos] floats, 256B-aligned
#define WS_COMPACT_OFF (((WS_INTS * 4) + 255) & ~255)
#define COMPACT_FLOATS ((size_t)(2 * CC) * NPOINTS)         // 7,372,800
#define WS_NEEDED      (WS_COMPACT_OFF + COMPACT_FLOATS * 4)

// ---- K0: zero histogram + write index passthroughs (as float) -------------
__global__ __launch_bounds__(256) void k0_zero_idx(
    const int* __restrict__ tIdx, const int* __restrict__ sIdx,
    const int* __restrict__ pIdx, float* __restrict__ outIdx,
    int* __restrict__ hist)
{
    const int gid = blockIdx.x * 256 + threadIdx.x;
    if (gid < NBUCKET) hist[gid] = 0;
    const int nT = BB * NN * NTF, nS = BB * NN * NSF, nP = NPOINTS;
    if (gid < nT)                 outIdx[gid] = (float)tIdx[gid];
    else if (gid < nT + nS)       outIdx[gid] = (float)sIdx[gid - nT];
    else if (gid < nT + nS + nP)  outIdx[gid] = (float)pIdx[gid - nT - nS];
}

// ---- K1: decode chain, bucket key, histogram ------------------------------
__global__ __launch_bounds__(256) void k1_prep(
    const int* __restrict__ tIdx, const int* __restrict__ sIdx,
    const int* __restrict__ pIdx,
    int* __restrict__ hist, int* __restrict__ key,
    int* __restrict__ rank, int* __restrict__ remArr,
    int* __restrict__ baseArr)
{
    const int pt = blockIdx.x * 256 + threadIdx.x;
    if (pt >= NPOINTS) return;
    const int b  = pt / (NN * PP);
    const int n  = (pt - b * NN * PP) >> 3;     // / PP
    const int bn = b * NN + n;

    const int pi  = pIdx[pt];
    const int s   = pi / (NTF * HW);
    const int rem = pi % HW;                    // h*W + w
    const int h   = rem / WW;
    const int w   = rem - h * WW;

    const int sp    = sIdx[bn * NSF + s];
    const int frame = tIdx[bn * NTF + sp];

    const int base = ((b * TT + frame) * CC) * HW + rem;   // c=0 elem offset
    const int k    = ((b * NTF + frame) * HH + h) * W16 + (w >> 4);
    const int r    = atomicAdd(&hist[k], 1);
    key[pt] = k; rank[pt] = r; remArr[pt] = rem; baseArr[pt] = base;
}

// ---- K2: exclusive scan of 4224 bucket counts (single block, shfl) --------
__global__ __launch_bounds__(256) void k2_scan(
    const int* __restrict__ hist, int* __restrict__ offs)
{
    __shared__ int wsum[4];
    const int t = threadIdx.x;
    const int lane = t & 63, wv = t >> 6;
    int local[SCAN_PER];
    int sum = 0;
    for (int i = 0; i < SCAN_PER; ++i) {
        const int idx = t * SCAN_PER + i;
        const int v = (idx < NBUCKET) ? hist[idx] : 0;
        local[i] = sum;           // exclusive within this thread's chunk
        sum += v;
    }
    // wave-inclusive scan of per-thread sums
    int incl = sum;
    for (int d = 1; d < 64; d <<= 1) {
        const int up = __shfl_up(incl, d, 64);
        if (lane >= d) incl += up;
    }
    if (lane == 63) wsum[wv] = incl;
    __syncthreads();
    int wpre = 0;
    for (int k = 0; k < 4; ++k) if (k < wv) wpre += wsum[k];
    const int base = wpre + incl - sum;   // exclusive prefix of this thread
    for (int i = 0; i < SCAN_PER; ++i) {
        const int idx = t * SCAN_PER + i;
        if (idx < NBUCKET) offs[idx] = base + local[i];
    }
    if (t == 255) offs[NBUCKET] = wpre + incl;  // total = NPOINTS sentinel
}

// ---- K3: scatter points into bucket-sorted order --------------------------
__global__ __launch_bounds__(256) void k3_scatter(
    const int* __restrict__ key, const int* __restrict__ rank,
    const int* __restrict__ remArr, const int* __restrict__ baseArr,
    const int* __restrict__ offs,
    int* __restrict__ sRem, int* __restrict__ sBase, int* __restrict__ sPt)
{
    const int pt = blockIdx.x * 256 + threadIdx.x;
    if (pt >= NPOINTS) return;
    const int pos = offs[key[pt]] + rank[pt];
    sRem[pos]  = remArr[pt];
    sBase[pos] = baseArr[pt];
    sPt[pos]   = pt;
}

// ---- K4a: persistent REGISTER-staged stream-gather ------------------------
// A/B experiment vs global_load_lds staging (which plateaued at ~3.0 TB/s
// delivered regardless of pipeline depth or L3-hit fraction): stage each
// 1408 B strip through VGPRs (f32x4 loads, the m13-proven 6.3 TB/s copy
// primitive), then ds_write into a per-wave ping-pong LDS slot, then the
// scattered ds_read gather + coalesced store as before. 4 rotating register
// sets, loads issued 3 items ahead; all vmcnt/lgkmcnt waits are left to the
// compiler's fine-grained counted insertion (it waits exactly on the set
// being consumed). LDS drops to 11264 B/block so occupancy is VGPR-bound.
#define PR_DECODE(IT)                                                          \
    const int q_     = q0 + (IT);                                              \
    const int slice_ = q_ & 31;                                                \
    const int cq_    = q_ >> 5;                                                \
    const int c_     = cq_ & 255;                                              \
    const int bfcam_ = cq_ >> 8;                                               \
    const int cam_   = (bfcam_ >= NBF) ? 1 : 0;

#define PR_LOAD(RA, RB, IT) {                                                  \
    PR_DECODE(IT)                                                              \
    const int bf_    = bfcam_ - cam_ * NBF;                                    \
    const int b_     = bf_ / NTF;                                              \
    const int fr_    = bf_ - b_ * NTF;                                         \
    const float* src_ = (cam_ ? cam1 : cam0)                                   \
        + (size_t)((b_ * TT + fr_) * CC + c_) * HW + slice_ * SLICE_FLOATS;    \
    RA = *(const f32x4*)(src_ + lane * 4);                                     \
    if (lane < (SLICE_F4 - 64)) RB = *(const f32x4*)(src_ + 256 + lane * 4);   \
}

#define PR_GATHER(RA, RB, IT) {                                                \
    PR_DECODE(IT)                                                              \
    float* lb_ = (float*)&rows4[wv][(IT) & 1][0];                              \
    ((f32x4*)lb_)[lane] = RA;                                                  \
    if (lane < (SLICE_F4 - 64)) ((f32x4*)lb_)[64 + lane] = RB;                 \
    const int br_ = slice_ * SLICE_FLOATS;                                     \
    float* dst_ = compact + (size_t)(cam_ * CC + c_) * NPOINTS;                \
    const int S_  = segS[IT];                                                  \
    const int E1_ = segE[IT] - 1;                                              \
    int jj0_ = S_ + lane;       if (jj0_ > E1_) jj0_ = E1_;                    \
    int jj1_ = S_ + 64 + lane;  if (jj1_ > E1_) jj1_ = E1_;                    \
    dst_[jj0_] = lb_[r0a[IT] - br_];                                           \
    dst_[jj1_] = lb_[r1a[IT] - br_];                                           \
}

__global__ __launch_bounds__(256) void k4_passA(
    const float* __restrict__ cam0, const float* __restrict__ cam1,
    const int* __restrict__ offs, const int* __restrict__ sRem,
    float* __restrict__ compact)
{
    __shared__ f32x4 rows4[4][2][SLICE_F4];   // 11264 B, per-wave ping-pong
    const int wv   = threadIdx.x >> 6;
    const int lane = threadIdx.x & 63;
    const int q0   = (blockIdx.x * 4 + wv) * ITEMS_PW;

    // ---- preload all per-item metadata ----
    int segS[ITEMS_PW], segE[ITEMS_PW], r0a[ITEMS_PW], r1a[ITEMS_PW];
#pragma unroll
    for (int it = 0; it < ITEMS_PW; ++it) {
        const int q_     = q0 + it;
        const int slice_ = q_ & 31;
        const int cq_    = q_ >> 5;
        const int bfcam_ = cq_ >> 8;
        const int cam_   = (bfcam_ >= NBF) ? 1 : 0;
        const int bf_    = bfcam_ - cam_ * NBF;
        const int bs_    = bf_ * BPF + slice_ * SLICE_BKT;
        segS[it] = offs[bs_];
        segE[it] = offs[bs_ + SLICE_BKT];
    }
#pragma unroll
    for (int it = 0; it < ITEMS_PW; ++it) {
        const int E1 = segE[it] - 1;
        int a0 = segS[it] + lane;       if (a0 > E1) a0 = E1;
        int a1 = segS[it] + 64 + lane;  if (a1 > E1) a1 = E1;
        r0a[it] = sRem[a0];
        r1a[it] = sRem[a1];
    }

    // ---- 4 rotating register sets, 3 items in flight ----
    f32x4 aA, bA, aB, bB, aC, bC, aD, bD;

    PR_LOAD(aA, bA, 0)
    PR_LOAD(aB, bB, 1)
    PR_LOAD(aC, bC, 2)

    PR_LOAD(aD, bD, 3)    PR_GATHER(aA, bA, 0)
    PR_LOAD(aA, bA, 4)    PR_GATHER(aB, bB, 1)
    PR_LOAD(aB, bB, 5)    PR_GATHER(aC, bC, 2)
    PR_LOAD(aC, bC, 6)    PR_GATHER(aD, bD, 3)
    PR_LOAD(aD, bD, 7)    PR_GATHER(aA, bA, 4)
    PR_LOAD(aA, bA, 8)    PR_GATHER(aB, bB, 5)
    PR_LOAD(aB, bB, 9)    PR_GATHER(aC, bC, 6)
    PR_LOAD(aC, bC, 10)   PR_GATHER(aD, bD, 7)
    PR_LOAD(aD, bD, 11)   PR_GATHER(aA, bA, 8)
                          PR_GATHER(aB, bB, 9)
                          PR_GATHER(aC, bC, 10)
                          PR_GATHER(aD, bD, 11)

    // ---- epilogue: segments longer than 128 points (essentially never) ----
#pragma unroll
    for (int it = 0; it < ITEMS_PW; ++it) {
        if (segE[it] - segS[it] > 128) {
            const int q_     = q0 + it;
            const int slice_ = q_ & 31;
            const int cq_    = q_ >> 5;
            const int c_     = cq_ & 255;
            const int bfcam_ = cq_ >> 8;
            const int cam_   = (bfcam_ >= NBF) ? 1 : 0;
            const int bf_    = bfcam_ - cam_ * NBF;
            const int b_     = bf_ / NTF;
            const int fr_    = bf_ - b_ * NTF;
            const float* srcrow = (cam_ ? cam1 : cam0)
                                + (size_t)((b_ * TT + fr_) * CC + c_) * HW;
            float* dst_ = compact + (size_t)(cam_ * CC + c_) * NPOINTS;
            for (int j = segS[it] + 128 + lane; j < segE[it]; j += 64)
                dst_[j] = srcrow[sRem[j]];
        }
    }
}

// ---- K5: permute compact -> out (round-0 form, plain cached accesses) -----
__global__ __launch_bounds__(256) void k5_passB(
    const float* __restrict__ compact, const int* __restrict__ sPt,
    float* __restrict__ out)
{
    const int sp0 = blockIdx.x * SPB;
    const int c   = threadIdx.x;

    int pts[SPB];
#pragma unroll
    for (int i = 0; i < SPB; ++i) pts[i] = sPt[sp0 + i];

    const float4* r0 = (const float4*)(compact + (size_t)c * NPOINTS + sp0);
    const float4* r1 = (const float4*)(compact + (size_t)(CC + c) * NPOINTS + sp0);
    float4 a0[SPB / 4], a1[SPB / 4];
#pragma unroll
    for (int q = 0; q < SPB / 4; ++q) { a0[q] = r0[q]; a1[q] = r1[q]; }

#pragma unroll
    for (int q = 0; q < SPB / 4; ++q) {
        const float v0[4] = {a0[q].x, a0[q].y, a0[q].z, a0[q].w};
        const float v1[4] = {a1[q].x, a1[q].y, a1[q].z, a1[q].w};
#pragma unroll
        for (int r = 0; r < 4; ++r) {
            const size_t ob = (size_t)pts[q * 4 + r] * (2 * CC);
            out[ob + c]      = v0[r];
            out[ob + CC + c] = v1[r];
        }
    }
}

// ---- K4b (fallback path): scattered gather in bucket-sorted order ---------
__global__ __launch_bounds__(256) void k4_gather(
    const float* __restrict__ cam0, const float* __restrict__ cam1,
    const int* __restrict__ sortedBase, const int* __restrict__ sortedPt,
    float* __restrict__ out)
{
    const int chunk = (blockIdx.x & 7) * (NGBLK / 8) + (blockIdx.x >> 3);
    const int c     = threadIdx.x;
    const int start = chunk * GATHER_G;

    int bases[GATHER_G], pts[GATHER_G];
#pragma unroll
    for (int g = 0; g < GATHER_G; ++g) {
        bases[g] = sortedBase[start + g];
        pts[g]   = sortedPt[start + g];
    }
    float v0[GATHER_G], v1[GATHER_G];
#pragma unroll
    for (int g = 0; g < GATHER_G; ++g) {
        v0[g] = cam0[bases[g] + c * HW];
        v1[g] = cam1[bases[g] + c * HW];
    }
#pragma unroll
    for (int g = 0; g < GATHER_G; ++g) {
        const int obase = pts[g] * (2 * CC);
        out[obase + c]      = v0[g];
        out[obase + CC + c] = v1[g];
    }
}

extern "C" void kernel_launch(void* const* d_in, const int* in_sizes, int n_in,
                              void* d_out, int out_size, void* d_ws, size_t ws_size,
                              hipStream_t stream) {
    const float* cam0 = (const float*)d_in[0];
    const float* cam1 = (const float*)d_in[1];
    // d_in[2] = anchor_centers (unused)
    const int* tIdx = (const int*)d_in[3];
    const int* sIdx = (const int*)d_in[4];
    const int* pIdx = (const int*)d_in[5];

    float* out = (float*)d_out;
    int*   ws  = (int*)d_ws;

    int* hist  = ws + WS_HIST;
    int* offs  = ws + WS_OFFS;
    int* key   = ws + WS_KEY;
    int* rank  = ws + WS_RANK;
    int* rem   = ws + WS_REM;
    int* baseA = ws + WS_BASE;
    int* sRem  = ws + WS_SREM;
    int* sBase = ws + WS_SBASE;
    int* sPt   = ws + WS_SPT;
    float* compact = (float*)((char*)d_ws + WS_COMPACT_OFF);

    const int nSampled = BB * NN * PP * 2 * CC;        // 7,372,800
    const int nIdxTot  = BB * NN * (NTF + NSF + PP);   // 25,200

    k0_zero_idx<<<(nIdxTot + 255) / 256, 256, 0, stream>>>(
        tIdx, sIdx, pIdx, out + nSampled, hist);

    k1_prep<<<(NPOINTS + 255) / 256, 256, 0, stream>>>(
        tIdx, sIdx, pIdx, hist, key, rank, rem, baseA);

    k2_scan<<<1, 256, 0, stream>>>(hist, offs);

    k3_scatter<<<(NPOINTS + 255) / 256, 256, 0, stream>>>(
        key, rank, rem, baseA, offs, sRem, sBase, sPt);

    if (ws_size >= WS_NEEDED) {
        k4_passA<<<PA_BLOCKS, 256, 0, stream>>>(cam0, cam1, offs, sRem, compact);
        k5_passB<<<NPOINTS / SPB, 256, 0, stream>>>(compact, sPt, out);
    } else {
        k4_gather<<<NGBLK, 256, 0, stream>>>(cam0, cam1, sBase, sPt, out);
    }
}

// Round 4
// 60.249 us; speedup vs baseline: 1.4062x; 1.0257x over previous
//
#include <hip/hip_runtime.h>

// Problem constants (from reference setup_inputs)
#define BB  2
#define TT  4
#define CC  256
#define HH  64
#define WW  176
#define NN  900
#define PP  8
#define NTF 3
#define NSF 3

#define HW        (HH * WW)              // 11264
#define NPOINTS   (BB * NN * PP)         // 14400
#define W16       11                     // ceil(176/16) line-buckets along w
#define NBUCKET   (BB * NTF * HH * W16)  // 4224
#define BPF       (HH * W16)             // 704 buckets per (b,frame)
#define SCAN_PER  17                     // 256*17 = 4352 >= 4224
#define GATHER_G  8
#define NGBLK     (NPOINTS / GATHER_G)   // 1800 (fallback path)
#define NBF       (BB * NTF)             // 6 (b,frame) images per cam
#define SPB       16                     // sorted points per block in pass B

// passA: 2-h-row slices (1.4 KB), persistent waves, async LDS pipeline.
// Round-4 change: 2x the waves, half the items per wave (concurrency probe).
#define HSL          2
#define SLICE_FLOATS (HSL * WW)          // 352
#define SLICE_F4     (SLICE_FLOATS / 4)  // 88
#define SLICE_BKT    (HSL * W16)         // 22 buckets per slice
#define SLICES       32                  // per (cam,bf,c) image-row
#define NITEMS       (2 * NBF * CC * SLICES)  // 98304 staging items
#define PA_BLOCKS    4096
#define PA_WAVES     (PA_BLOCKS * 4)     // 16384
#define ITEMS_PW     (NITEMS / PA_WAVES) // 6
#define DEPTH        4                   // LDS slots (3-ahead issue)

// native vector type
typedef float f32x4 __attribute__((ext_vector_type(4)));

// ws layout (int32 slots)
#define WS_HIST   0
#define WS_OFFS   (WS_HIST + NBUCKET)
#define WS_KEY    (WS_OFFS + NBUCKET + 1)   // +1: sentinel offs[NBUCKET]=NPOINTS
#define WS_RANK   (WS_KEY + NPOINTS)
#define WS_REM    (WS_RANK + NPOINTS)
#define WS_BASE   (WS_REM + NPOINTS)
#define WS_SREM   (WS_BASE + NPOINTS)
#define WS_SBASE  (WS_SREM + NPOINTS)
#define WS_SPT    (WS_SBASE + NPOINTS)
#define WS_INTS   (WS_SPT + NPOINTS)
// compact buffer: [cam*256+c][sortedPos] floats, 256B-aligned
#define WS_COMPACT_OFF (((WS_INTS * 4) + 255) & ~255)
#define COMPACT_FLOATS ((size_t)(2 * CC) * NPOINTS)         // 7,372,800
#define WS_NEEDED      (WS_COMPACT_OFF + COMPACT_FLOATS * 4)

// ---- K0: zero histogram + write index passthroughs (as float) -------------
__global__ __launch_bounds__(256) void k0_zero_idx(
    const int* __restrict__ tIdx, const int* __restrict__ sIdx,
    const int* __restrict__ pIdx, float* __restrict__ outIdx,
    int* __restrict__ hist)
{
    const int gid = blockIdx.x * 256 + threadIdx.x;
    if (gid < NBUCKET) hist[gid] = 0;
    const int nT = BB * NN * NTF, nS = BB * NN * NSF, nP = NPOINTS;
    if (gid < nT)                 outIdx[gid] = (float)tIdx[gid];
    else if (gid < nT + nS)       outIdx[gid] = (float)sIdx[gid - nT];
    else if (gid < nT + nS + nP)  outIdx[gid] = (float)pIdx[gid - nT - nS];
}

// ---- K1: decode chain, bucket key, histogram ------------------------------
__global__ __launch_bounds__(256) void k1_prep(
    const int* __restrict__ tIdx, const int* __restrict__ sIdx,
    const int* __restrict__ pIdx,
    int* __restrict__ hist, int* __restrict__ key,
    int* __restrict__ rank, int* __restrict__ remArr,
    int* __restrict__ baseArr)
{
    const int pt = blockIdx.x * 256 + threadIdx.x;
    if (pt >= NPOINTS) return;
    const int b  = pt / (NN * PP);
    const int n  = (pt - b * NN * PP) >> 3;     // / PP
    const int bn = b * NN + n;

    const int pi  = pIdx[pt];
    const int s   = pi / (NTF * HW);
    const int rem = pi % HW;                    // h*W + w
    const int h   = rem / WW;
    const int w   = rem - h * WW;

    const int sp    = sIdx[bn * NSF + s];
    const int frame = tIdx[bn * NTF + sp];

    const int base = ((b * TT + frame) * CC) * HW + rem;   // c=0 elem offset
    const int k    = ((b * NTF + frame) * HH + h) * W16 + (w >> 4);
    const int r    = atomicAdd(&hist[k], 1);
    key[pt] = k; rank[pt] = r; remArr[pt] = rem; baseArr[pt] = base;
}

// ---- K2: exclusive scan of 4224 bucket counts (single block, shfl) --------
__global__ __launch_bounds__(256) void k2_scan(
    const int* __restrict__ hist, int* __restrict__ offs)
{
    __shared__ int wsum[4];
    const int t = threadIdx.x;
    const int lane = t & 63, wv = t >> 6;
    int local[SCAN_PER];
    int sum = 0;
    for (int i = 0; i < SCAN_PER; ++i) {
        const int idx = t * SCAN_PER + i;
        const int v = (idx < NBUCKET) ? hist[idx] : 0;
        local[i] = sum;           // exclusive within this thread's chunk
        sum += v;
    }
    // wave-inclusive scan of per-thread sums
    int incl = sum;
    for (int d = 1; d < 64; d <<= 1) {
        const int up = __shfl_up(incl, d, 64);
        if (lane >= d) incl += up;
    }
    if (lane == 63) wsum[wv] = incl;
    __syncthreads();
    int wpre = 0;
    for (int k = 0; k < 4; ++k) if (k < wv) wpre += wsum[k];
    const int base = wpre + incl - sum;   // exclusive prefix of this thread
    for (int i = 0; i < SCAN_PER; ++i) {
        const int idx = t * SCAN_PER + i;
        if (idx < NBUCKET) offs[idx] = base + local[i];
    }
    if (t == 255) offs[NBUCKET] = wpre + incl;  // total = NPOINTS sentinel
}

// ---- K3: scatter points into bucket-sorted order --------------------------
__global__ __launch_bounds__(256) void k3_scatter(
    const int* __restrict__ key, const int* __restrict__ rank,
    const int* __restrict__ remArr, const int* __restrict__ baseArr,
    const int* __restrict__ offs,
    int* __restrict__ sRem, int* __restrict__ sBase, int* __restrict__ sPt)
{
    const int pt = blockIdx.x * 256 + threadIdx.x;
    if (pt >= NPOINTS) return;
    const int pos = offs[key[pt]] + rank[pt];
    sRem[pos]  = remArr[pt];
    sBase[pos] = baseArr[pt];
    sPt[pos]   = pt;
}

// ---- K4a: persistent async stream-gather, concurrency-scaled --------------
// Concurrency probe: 16384 waves (2x) with 6 items each (0.5x). Metadata
// register arrays halve (24 regs), raising the VGPR wave/SIMD cap; 16
// blocks/CU available so residency is limited only by VGPR/LDS. Pipeline
// identical to the verified round-0 structure: global_load_lds staging,
// DEPTH=4 slots, 3 items in flight, exact FIFO-derived counted waits
// (2 loads + 2 stores per item -> 6,8,10 | 10,8,6, never 0 in stream).
#define GLOAD_LDS(GP, LP)                                                      \
    __builtin_amdgcn_global_load_lds(                                          \
        (const __attribute__((address_space(1))) void*)(GP),                   \
        (__attribute__((address_space(3))) void*)(LP), 16, 0, 0)

#define PA_ISSUE(SLOT, IT) {                                                   \
    const int q_     = q0 + (IT);                                              \
    const int slice_ = q_ & 31;                                                \
    const int cq_    = q_ >> 5;                                                \
    const int c_     = cq_ & 255;                                              \
    const int bfcam_ = cq_ >> 8;                                               \
    const int cam_   = (bfcam_ >= NBF) ? 1 : 0;                                \
    const int bf_    = bfcam_ - cam_ * NBF;                                    \
    const int b_     = bf_ / NTF;                                              \
    const int fr_    = bf_ - b_ * NTF;                                         \
    const float* src_ = (cam_ ? cam1 : cam0)                                   \
        + (size_t)((b_ * TT + fr_) * CC + c_) * HW + slice_ * SLICE_FLOATS;    \
    GLOAD_LDS(src_ + lane * 4, &rows[wv][SLOT][0]);                            \
    if (lane < (SLICE_F4 - 64)) GLOAD_LDS(src_ + 256 + lane * 4,               \
                                          &rows[wv][SLOT][256]);               \
}

#define PA_GATHER(SLOT, IT, NW) {                                              \
    asm volatile("s_waitcnt vmcnt(" #NW ")" ::: "memory");                     \
    const int q_     = q0 + (IT);                                              \
    const int slice_ = q_ & 31;                                                \
    const int cq_    = q_ >> 5;                                                \
    const int c_     = cq_ & 255;                                              \
    const int bfcam_ = cq_ >> 8;                                               \
    const int cam_   = (bfcam_ >= NBF) ? 1 : 0;                                \
    const int br_    = slice_ * SLICE_FLOATS;                                  \
    float* dst_ = compact + (size_t)(cam_ * CC + c_) * NPOINTS;                \
    const int S_  = segS[IT];                                                  \
    const int E1_ = segE[IT] - 1;                                              \
    int jj0_ = S_ + lane;       if (jj0_ > E1_) jj0_ = E1_;                    \
    int jj1_ = S_ + 64 + lane;  if (jj1_ > E1_) jj1_ = E1_;                    \
    dst_[jj0_] = rows[wv][SLOT][r0a[IT] - br_];                                \
    dst_[jj1_] = rows[wv][SLOT][r1a[IT] - br_];                                \
}

__global__ __launch_bounds__(256) void k4_passA(
    const float* __restrict__ cam0, const float* __restrict__ cam1,
    const int* __restrict__ offs, const int* __restrict__ sRem,
    float* __restrict__ compact)
{
    __shared__ float rows[4][DEPTH][SLICE_FLOATS];   // 22528 B
    const int wv   = threadIdx.x >> 6;
    const int lane = threadIdx.x & 63;
    const int q0   = (blockIdx.x * 4 + wv) * ITEMS_PW;

    // ---- preload all per-item metadata (keeps vmcnt stream clean after) ---
    int segS[ITEMS_PW], segE[ITEMS_PW], r0a[ITEMS_PW], r1a[ITEMS_PW];
#pragma unroll
    for (int it = 0; it < ITEMS_PW; ++it) {
        const int q_     = q0 + it;
        const int slice_ = q_ & 31;
        const int cq_    = q_ >> 5;
        const int bfcam_ = cq_ >> 8;
        const int cam_   = (bfcam_ >= NBF) ? 1 : 0;
        const int bf_    = bfcam_ - cam_ * NBF;
        const int bs_    = bf_ * BPF + slice_ * SLICE_BKT;
        segS[it] = offs[bs_];
        segE[it] = offs[bs_ + SLICE_BKT];
    }
#pragma unroll
    for (int it = 0; it < ITEMS_PW; ++it) {
        const int E1 = segE[it] - 1;
        int a0 = segS[it] + lane;       if (a0 > E1) a0 = E1;
        int a1 = segS[it] + 64 + lane;  if (a1 > E1) a1 = E1;
        r0a[it] = sRem[a0];
        r1a[it] = sRem[a1];
    }
    asm volatile("s_waitcnt vmcnt(0)" ::: "memory");

    // ---- prologue: 3 items in flight ----
    PA_ISSUE(0, 0)
    PA_ISSUE(1, 1)
    PA_ISSUE(2, 2)

    // ---- steady state + drain, exact counted waits ----
    PA_ISSUE(3, 3)   PA_GATHER(0, 0, 6)
    PA_ISSUE(0, 4)   PA_GATHER(1, 1, 8)
    PA_ISSUE(1, 5)   PA_GATHER(2, 2, 10)
                     PA_GATHER(3, 3, 10)
                     PA_GATHER(0, 4, 8)
                     PA_GATHER(1, 5, 6)

    // ---- epilogue: segments longer than 128 points (essentially never) ----
    asm volatile("s_waitcnt vmcnt(0)" ::: "memory");
#pragma unroll
    for (int it = 0; it < ITEMS_PW; ++it) {
        if (segE[it] - segS[it] > 128) {
            const int q_     = q0 + it;
            const int slice_ = q_ & 31;
            const int cq_    = q_ >> 5;
            const int c_     = cq_ & 255;
            const int bfcam_ = cq_ >> 8;
            const int cam_   = (bfcam_ >= NBF) ? 1 : 0;
            const int bf_    = bfcam_ - cam_ * NBF;
            const int b_     = bf_ / NTF;
            const int fr_    = bf_ - b_ * NTF;
            const float* srcrow = (cam_ ? cam1 : cam0)
                                + (size_t)((b_ * TT + fr_) * CC + c_) * HW;
            float* dst_ = compact + (size_t)(cam_ * CC + c_) * NPOINTS;
            for (int j = segS[it] + 128 + lane; j < segE[it]; j += 64)
                dst_[j] = srcrow[sRem[j]];
        }
    }
}

// ---- K5: permute compact -> out (round-0 form, plain cached accesses) -----
__global__ __launch_bounds__(256) void k5_passB(
    const float* __restrict__ compact, const int* __restrict__ sPt,
    float* __restrict__ out)
{
    const int sp0 = blockIdx.x * SPB;
    const int c   = threadIdx.x;

    int pts[SPB];
#pragma unroll
    for (int i = 0; i < SPB; ++i) pts[i] = sPt[sp0 + i];

    const float4* r0 = (const float4*)(compact + (size_t)c * NPOINTS + sp0);
    const float4* r1 = (const float4*)(compact + (size_t)(CC + c) * NPOINTS + sp0);
    float4 a0[SPB / 4], a1[SPB / 4];
#pragma unroll
    for (int q = 0; q < SPB / 4; ++q) { a0[q] = r0[q]; a1[q] = r1[q]; }

#pragma unroll
    for (int q = 0; q < SPB / 4; ++q) {
        const float v0[4] = {a0[q].x, a0[q].y, a0[q].z, a0[q].w};
        const float v1[4] = {a1[q].x, a1[q].y, a1[q].z, a1[q].w};
#pragma unroll
        for (int r = 0; r < 4; ++r) {
            const size_t ob = (size_t)pts[q * 4 + r] * (2 * CC);
            out[ob + c]      = v0[r];
            out[ob + CC + c] = v1[r];
        }
    }
}

// ---- K4b (fallback path): scattered gather in bucket-sorted order ---------
__global__ __launch_bounds__(256) void k4_gather(
    const float* __restrict__ cam0, const float* __restrict__ cam1,
    const int* __restrict__ sortedBase, const int* __restrict__ sortedPt,
    float* __restrict__ out)
{
    const int chunk = (blockIdx.x & 7) * (NGBLK / 8) + (blockIdx.x >> 3);
    const int c     = threadIdx.x;
    const int start = chunk * GATHER_G;

    int bases[GATHER_G], pts[GATHER_G];
#pragma unroll
    for (int g = 0; g < GATHER_G; ++g) {
        bases[g] = sortedBase[start + g];
        pts[g]   = sortedPt[start + g];
    }
    float v0[GATHER_G], v1[GATHER_G];
#pragma unroll
    for (int g = 0; g < GATHER_G; ++g) {
        v0[g] = cam0[bases[g] + c * HW];
        v1[g] = cam1[bases[g] + c * HW];
    }
#pragma unroll
    for (int g = 0; g < GATHER_G; ++g) {
        const int obase = pts[g] * (2 * CC);
        out[obase + c]      = v0[g];
        out[obase + CC + c] = v1[g];
    }
}

extern "C" void kernel_launch(void* const* d_in, const int* in_sizes, int n_in,
                              void* d_out, int out_size, void* d_ws, size_t ws_size,
                              hipStream_t stream) {
    const float* cam0 = (const float*)d_in[0];
    const float* cam1 = (const float*)d_in[1];
    // d_in[2] = anchor_centers (unused)
    const int* tIdx = (const int*)d_in[3];
    const int* sIdx = (const int*)d_in[4];
    const int* pIdx = (const int*)d_in[5];

    float* out = (float*)d_out;
    int*   ws  = (int*)d_ws;

    int* hist  = ws + WS_HIST;
    int* offs  = ws + WS_OFFS;
    int* key   = ws + WS_KEY;
    int* rank  = ws + WS_RANK;
    int* rem   = ws + WS_REM;
    int* baseA = ws + WS_BASE;
    int* sRem  = ws + WS_SREM;
    int* sBase = ws + WS_SBASE;
    int* sPt   = ws + WS_SPT;
    float* compact = (float*)((char*)d_ws + WS_COMPACT_OFF);

    const int nSampled = BB * NN * PP * 2 * CC;        // 7,372,800
    const int nIdxTot  = BB * NN * (NTF + NSF + PP);   // 25,200

    k0_zero_idx<<<(nIdxTot + 255) / 256, 256, 0, stream>>>(
        tIdx, sIdx, pIdx, out + nSampled, hist);

    k1_prep<<<(NPOINTS + 255) / 256, 256, 0, stream>>>(
        tIdx, sIdx, pIdx, hist, key, rank, rem, baseA);

    k2_scan<<<1, 256, 0, stream>>>(hist, offs);

    k3_scatter<<<(NPOINTS + 255) / 256, 256, 0, stream>>>(
        key, rank, rem, baseA, offs, sRem, sBase, sPt);

    if (ws_size >= WS_NEEDED) {
        k4_passA<<<PA_BLOCKS, 256, 0, stream>>>(cam0, cam1, offs, sRem, compact);
        k5_passB<<<NPOINTS / SPB, 256, 0, stream>>>(compact, sPt, out);
    } else {
        k4_gather<<<NGBLK, 256, 0, stream>>>(cam0, cam1, sBase, sPt, out);
    }
}

// Round 5
// 49.407 us; speedup vs baseline: 1.7148x; 1.2194x over previous
//
#include <hip/hip_runtime.h>

// Problem constants (from reference setup_inputs)
#define BB  2
#define TT  4
#define CC  256
#define HH  64
#define WW  176
#define NN  900
#define PP  8
#define NTF 3
#define NSF 3

#define HW        (HH * WW)              // 11264
#define NPOINTS   (BB * NN * PP)         // 14400
#define W16       11                     // ceil(176/16) line-buckets along w
#define NBUCKET   (BB * NTF * HH * W16)  // 4224
#define BPF       (HH * W16)             // 704 buckets per (b,frame)
#define SCAN_PER  17                     // 256*17 = 4352 >= 4224
#define GATHER_G  8
#define NGBLK     (NPOINTS / GATHER_G)   // 1800 (fallback path)
#define NBF       (BB * NTF)             // 6 (b,frame) images per cam

// fused pass: block = (cam, bf, h-row); 8 chunks of 32 channels staged in
// padded LDS; points of that (bf,h) bucket write out directly.
#define CCH    32                        // channels per chunk
#define NCH    (CC / CCH)                // 8
#define WPAD   180                       // padded strip stride (floats)
#define CAPM   192                       // cached point-meta capacity (λ≈37.5)

// native vector type
typedef float f32x4 __attribute__((ext_vector_type(4)));

// ws layout (int32 slots)
#define WS_HIST   0
#define WS_OFFS   (WS_HIST + NBUCKET)
#define WS_KEY    (WS_OFFS + NBUCKET + 1)   // +1: sentinel offs[NBUCKET]=NPOINTS
#define WS_RANK   (WS_KEY + NPOINTS)
#define WS_REM    (WS_RANK + NPOINTS)
#define WS_BASE   (WS_REM + NPOINTS)
#define WS_SREM   (WS_BASE + NPOINTS)
#define WS_SBASE  (WS_SREM + NPOINTS)
#define WS_SPT    (WS_SBASE + NPOINTS)
#define WS_INTS   (WS_SPT + NPOINTS)
#define WS_MIN    ((size_t)WS_INTS * 4)

// ---- K0: zero histogram + write index passthroughs (as float) -------------
__global__ __launch_bounds__(256) void k0_zero_idx(
    const int* __restrict__ tIdx, const int* __restrict__ sIdx,
    const int* __restrict__ pIdx, float* __restrict__ outIdx,
    int* __restrict__ hist)
{
    const int gid = blockIdx.x * 256 + threadIdx.x;
    if (gid < NBUCKET) hist[gid] = 0;
    const int nT = BB * NN * NTF, nS = BB * NN * NSF, nP = NPOINTS;
    if (gid < nT)                 outIdx[gid] = (float)tIdx[gid];
    else if (gid < nT + nS)       outIdx[gid] = (float)sIdx[gid - nT];
    else if (gid < nT + nS + nP)  outIdx[gid] = (float)pIdx[gid - nT - nS];
}

// ---- K1: decode chain, bucket key, histogram ------------------------------
__global__ __launch_bounds__(256) void k1_prep(
    const int* __restrict__ tIdx, const int* __restrict__ sIdx,
    const int* __restrict__ pIdx,
    int* __restrict__ hist, int* __restrict__ key,
    int* __restrict__ rank, int* __restrict__ remArr,
    int* __restrict__ baseArr)
{
    const int pt = blockIdx.x * 256 + threadIdx.x;
    if (pt >= NPOINTS) return;
    const int b  = pt / (NN * PP);
    const int n  = (pt - b * NN * PP) >> 3;     // / PP
    const int bn = b * NN + n;

    const int pi  = pIdx[pt];
    const int s   = pi / (NTF * HW);
    const int rem = pi % HW;                    // h*W + w
    const int h   = rem / WW;
    const int w   = rem - h * WW;

    const int sp    = sIdx[bn * NSF + s];
    const int frame = tIdx[bn * NTF + sp];

    const int base = ((b * TT + frame) * CC) * HW + rem;   // c=0 elem offset
    const int k    = ((b * NTF + frame) * HH + h) * W16 + (w >> 4);
    const int r    = atomicAdd(&hist[k], 1);
    key[pt] = k; rank[pt] = r; remArr[pt] = rem; baseArr[pt] = base;
}

// ---- K2: exclusive scan of 4224 bucket counts (single block, shfl) --------
__global__ __launch_bounds__(256) void k2_scan(
    const int* __restrict__ hist, int* __restrict__ offs)
{
    __shared__ int wsum[4];
    const int t = threadIdx.x;
    const int lane = t & 63, wv = t >> 6;
    int local[SCAN_PER];
    int sum = 0;
    for (int i = 0; i < SCAN_PER; ++i) {
        const int idx = t * SCAN_PER + i;
        const int v = (idx < NBUCKET) ? hist[idx] : 0;
        local[i] = sum;           // exclusive within this thread's chunk
        sum += v;
    }
    // wave-inclusive scan of per-thread sums
    int incl = sum;
    for (int d = 1; d < 64; d <<= 1) {
        const int up = __shfl_up(incl, d, 64);
        if (lane >= d) incl += up;
    }
    if (lane == 63) wsum[wv] = incl;
    __syncthreads();
    int wpre = 0;
    for (int k = 0; k < 4; ++k) if (k < wv) wpre += wsum[k];
    const int base = wpre + incl - sum;   // exclusive prefix of this thread
    for (int i = 0; i < SCAN_PER; ++i) {
        const int idx = t * SCAN_PER + i;
        if (idx < NBUCKET) offs[idx] = base + local[i];
    }
    if (t == 255) offs[NBUCKET] = wpre + incl;  // total = NPOINTS sentinel
}

// ---- K3: scatter points into bucket-sorted order --------------------------
__global__ __launch_bounds__(256) void k3_scatter(
    const int* __restrict__ key, const int* __restrict__ rank,
    const int* __restrict__ remArr, const int* __restrict__ baseArr,
    const int* __restrict__ offs,
    int* __restrict__ sRem, int* __restrict__ sBase, int* __restrict__ sPt)
{
    const int pt = blockIdx.x * 256 + threadIdx.x;
    if (pt >= NPOINTS) return;
    const int pos = offs[key[pt]] + rank[pt];
    sRem[pos]  = remArr[pt];
    sBase[pos] = baseArr[pt];
    sPt[pos]   = pt;
}

// ---- K4 fused: stream (cam,bf,h) strips through LDS, write out directly ---
// Block (cam, bf, h): for each of 8 chunks of 32 channels, stage the 32
// strips (176 floats each, padded to 180 to break the 16-float bank cycle)
// in a double-buffered LDS tile, then each half-wave writes one point's
// 32-channel out segment (128 B contiguous). Eliminates the compact buffer
// and the k5 permute pass entirely: traffic 248 MB -> 168 MB.
// Register-staged loads with issue-early/write-late split (T14); ONE raw
// barrier per chunk (double-buffer separation makes the post-gather barrier
// redundant: a wave's pre-barrier lgkmcnt(0) covers both its gather reads
// and its next-chunk ds_writes, so buffer p cannot be overwritten (chunk
// k+2) until every wave passed barrier k+1, which requires gather(k) done).

#define LOADR(R, CH) {                                                         \
    const float* s_ = img + (size_t)((CH) * CCH + strip) * HW;                 \
    _Pragma("unroll")                                                          \
    for (int u = 0; u < 6; ++u) {                                              \
        const int p4 = l8 + 8 * u;                                             \
        if (p4 < 44) R[u] = *(const f32x4*)(s_ + p4 * 4);                      \
    }                                                                          \
}

#define DSWR(R, P) {                                                           \
    float* d_ = &strips[P][strip * WPAD];                                      \
    _Pragma("unroll")                                                          \
    for (int u = 0; u < 6; ++u) {                                              \
        const int p4 = l8 + 8 * u;                                             \
        if (p4 < 44) *(f32x4*)(d_ + p4 * 4) = R[u];                            \
    }                                                                          \
}

#define GATH(CH, P) {                                                          \
    const int ob_ = cam * CC + (CH) * CCH + cl;                                \
    for (int it2 = wv * 2; it2 < np; it2 += 8) {                               \
        const int jl = it2 + ph;                                               \
        const int jc = (jl < np) ? jl : (np - 1);                              \
        int w_, pt_;                                                           \
        if (jc < CAPM) { w_ = w_s[jc]; pt_ = pt_s[jc]; }                       \
        else { w_ = sRem[S + jc] - h * WW; pt_ = sPt[S + jc]; }                \
        const float v_ = strips[P][cl * WPAD + w_];                            \
        if (jl < np) out[(size_t)pt_ * (2 * CC) + ob_] = v_;                   \
    }                                                                          \
}

#define CHUNK_BARRIER()                                                        \
    asm volatile("s_waitcnt lgkmcnt(0)" ::: "memory");                         \
    __builtin_amdgcn_s_barrier();

__global__ __launch_bounds__(256) void k4_fused(
    const float* __restrict__ cam0, const float* __restrict__ cam1,
    const int* __restrict__ offs, const int* __restrict__ sRem,
    const int* __restrict__ sPt, float* __restrict__ out)
{
    __shared__ float strips[2][CCH * WPAD];   // 2 x 23040 B
    __shared__ int w_s[CAPM], pt_s[CAPM];     // +1536 B  => 47616 B/block

    const int tid  = threadIdx.x;
    const int lane = tid & 63, wv = tid >> 6;
    const int cl   = lane & 31, ph = lane >> 5;   // channel-lane, point-half

    const int h     = blockIdx.x & 63;
    const int bfcam = blockIdx.x >> 6;            // [0,12)
    const int cam   = (bfcam >= NBF) ? 1 : 0;
    const int bf    = bfcam - cam * NBF;
    const int b     = bf / NTF;
    const int fr    = bf - b * NTF;
    const float* img = (cam ? cam1 : cam0)
                     + (size_t)((b * TT + fr) * CC) * HW + h * WW;

    const int S  = offs[bf * BPF + h * W16];
    const int E  = offs[bf * BPF + h * W16 + W16];
    const int np = E - S;

    // point metadata -> LDS (visible after the first chunk barrier)
    for (int j = tid; j < np && j < CAPM; j += 256) {
        w_s[j]  = sRem[S + j] - h * WW;
        pt_s[j] = sPt[S + j];
    }

    const int strip = tid >> 3;   // 0..31: channel within chunk
    const int l8    = tid & 7;

    f32x4 RA[6], RB[6];

    LOADR(RA, 0)
    DSWR(RA, 0)     LOADR(RB, 1)
    CHUNK_BARRIER() GATH(0, 0)
    DSWR(RB, 1)     LOADR(RA, 2)
    CHUNK_BARRIER() GATH(1, 1)
    DSWR(RA, 0)     LOADR(RB, 3)
    CHUNK_BARRIER() GATH(2, 0)
    DSWR(RB, 1)     LOADR(RA, 4)
    CHUNK_BARRIER() GATH(3, 1)
    DSWR(RA, 0)     LOADR(RB, 5)
    CHUNK_BARRIER() GATH(4, 0)
    DSWR(RB, 1)     LOADR(RA, 6)
    CHUNK_BARRIER() GATH(5, 1)
    DSWR(RA, 0)     LOADR(RB, 7)
    CHUNK_BARRIER() GATH(6, 0)
    DSWR(RB, 1)
    CHUNK_BARRIER() GATH(7, 1)
}

// ---- K4b (fallback path): scattered gather in bucket-sorted order ---------
__global__ __launch_bounds__(256) void k4_gather(
    const float* __restrict__ cam0, const float* __restrict__ cam1,
    const int* __restrict__ sortedBase, const int* __restrict__ sortedPt,
    float* __restrict__ out)
{
    const int chunk = (blockIdx.x & 7) * (NGBLK / 8) + (blockIdx.x >> 3);
    const int c     = threadIdx.x;
    const int start = chunk * GATHER_G;

    int bases[GATHER_G], pts[GATHER_G];
#pragma unroll
    for (int g = 0; g < GATHER_G; ++g) {
        bases[g] = sortedBase[start + g];
        pts[g]   = sortedPt[start + g];
    }
    float v0[GATHER_G], v1[GATHER_G];
#pragma unroll
    for (int g = 0; g < GATHER_G; ++g) {
        v0[g] = cam0[bases[g] + c * HW];
        v1[g] = cam1[bases[g] + c * HW];
    }
#pragma unroll
    for (int g = 0; g < GATHER_G; ++g) {
        const int obase = pts[g] * (2 * CC);
        out[obase + c]      = v0[g];
        out[obase + CC + c] = v1[g];
    }
}

extern "C" void kernel_launch(void* const* d_in, const int* in_sizes, int n_in,
                              void* d_out, int out_size, void* d_ws, size_t ws_size,
                              hipStream_t stream) {
    const float* cam0 = (const float*)d_in[0];
    const float* cam1 = (const float*)d_in[1];
    // d_in[2] = anchor_centers (unused)
    const int* tIdx = (const int*)d_in[3];
    const int* sIdx = (const int*)d_in[4];
    const int* pIdx = (const int*)d_in[5];

    float* out = (float*)d_out;
    int*   ws  = (int*)d_ws;

    int* hist  = ws + WS_HIST;
    int* offs  = ws + WS_OFFS;
    int* key   = ws + WS_KEY;
    int* rank  = ws + WS_RANK;
    int* rem   = ws + WS_REM;
    int* baseA = ws + WS_BASE;
    int* sRem  = ws + WS_SREM;
    int* sBase = ws + WS_SBASE;
    int* sPt   = ws + WS_SPT;

    const int nSampled = BB * NN * PP * 2 * CC;        // 7,372,800
    const int nIdxTot  = BB * NN * (NTF + NSF + PP);   // 25,200

    k0_zero_idx<<<(nIdxTot + 255) / 256, 256, 0, stream>>>(
        tIdx, sIdx, pIdx, out + nSampled, hist);

    k1_prep<<<(NPOINTS + 255) / 256, 256, 0, stream>>>(
        tIdx, sIdx, pIdx, hist, key, rank, rem, baseA);

    k2_scan<<<1, 256, 0, stream>>>(hist, offs);

    k3_scatter<<<(NPOINTS + 255) / 256, 256, 0, stream>>>(
        key, rank, rem, baseA, offs, sRem, sBase, sPt);

    if (ws_size >= WS_MIN) {
        k4_fused<<<2 * NBF * HH, 256, 0, stream>>>(cam0, cam1, offs, sRem, sPt, out);
    } else {
        k4_gather<<<NGBLK, 256, 0, stream>>>(cam0, cam1, sBase, sPt, out);
    }
}